// Round 5
// baseline (231.827 us; speedup 1.0000x reference)
//
#include <hip/hip_runtime.h>

// BackwardRPM: 16384 independent solves, 200 steps of
//   u <- clip(u - LR * (R^T (R (tanh(u W1 + b1) W2 + b2 - spec)))[:6])
// Algebra: Qs[unit][j] = -LR * (W2 R^T R[:, :6])[unit][j];
//   es[j] = -LR * sum_p R[p][j] z[p],  z[p] = sum_k R[p][k](b2[k]-spec[k]).
//   Step: t = K*(u W1 + b1); r = rcp(exp2(t)+1)  [tanh = 1-2r];
//   u = clip(u + es + sum_units (Qs + r*(-2 Qs))).
//
// R5 design decisions (from R1-R4 post-mortems):
//  * 16 threads/sample, 4 hidden units each: 58 constant floats/thread --
//    fits ANY allocator budget; R1(214 consts)/R2-R4(110) got remat/spilled.
//  * Pure scalar f32: R4's v2f ext-vector code scalarized with mov churn
//    (~2.6x VALU inflation). Known-good codegen beats theoretical pk rate.
//  * ZERO LDS: constants computed per-thread from global (L1-cached, tiny).
//    Removes remat-from-LDS and all bank conflicts (R2-R4: 147k-507k).
//  * amdgpu_waves_per_eu(4,4) matches grid exactly: 4096 waves/1024 SIMDs.
//  * Reduction: 4-stage DPP butterfly over 16-lane group, masks {1,2,7,15}
//    (quad_perm B1, quad_perm 4E, row_half_mirror 141, row_mirror 140).

static constexpr float LR_ = 0.01f;

template <int CTRL>
__device__ __forceinline__ float dppx(float x) {
    return __int_as_float(
        __builtin_amdgcn_mov_dpp(__float_as_int(x), CTRL, 0xF, 0xF, true));
}

__global__ __launch_bounds__(256)
__attribute__((amdgpu_waves_per_eu(4, 4)))
void solve_k(const float* __restrict__ spec, const float* __restrict__ W1,
             const float* __restrict__ b1,   const float* __restrict__ W2,
             const float* __restrict__ b2,   const float* __restrict__ R,
             float* __restrict__ out, int batch)
{
    const int tid = blockIdx.x * 256 + threadIdx.x;
    const int s   = tid >> 4;    // sample
    const int sub = tid & 15;    // 16-lane group position
    const int ib  = sub * 4;     // first of my 4 hidden units
    const bool live = (s < batch);
    const int sl = live ? s : 0;
    const float K = 2.8853900817779268f;  // 2*log2(e)

    // ---- per-thread constants (all from global; nothing to remat from) ----
    float w1k[4][6], b1k[4];
    #pragma unroll
    for (int i = 0; i < 4; ++i) {
        b1k[i] = K * b1[ib + i];
        #pragma unroll
        for (int j = 0; j < 6; ++j)
            w1k[i][j] = K * W1[j*64 + ib + i];   // W1 is (6,64) row-major
    }

    // z[p] = sum_k R[p][k] * (b2[k] - spec[k])
    float z[8];
    #pragma unroll
    for (int p = 0; p < 8; ++p) z[p] = 0.f;
    const float* sp = spec + sl * 40;
    for (int k = 0; k < 40; ++k) {
        float v = b2[k] - sp[k];
        #pragma unroll
        for (int p = 0; p < 8; ++p) z[p] = fmaf(R[p*40+k], v, z[p]);
    }

    // Qs rows for my 4 units; qs2 = -2*Qs, qc[j] = sum_{my units} Qs[i][j]
    float qs2[4][6], qc[6];
    #pragma unroll
    for (int j = 0; j < 6; ++j) qc[j] = 0.f;
    #pragma unroll
    for (int i = 0; i < 4; ++i) {
        const float* w2r = W2 + (ib + i) * 40;
        float M[8];
        #pragma unroll
        for (int p = 0; p < 8; ++p) M[p] = 0.f;
        for (int k = 0; k < 40; ++k) {
            float wv = w2r[k];
            #pragma unroll
            for (int p = 0; p < 8; ++p) M[p] = fmaf(R[p*40+k], wv, M[p]);
        }
        #pragma unroll
        for (int j = 0; j < 6; ++j) {
            float acc = 0.f;
            #pragma unroll
            for (int p = 0; p < 8; ++p) acc = fmaf(M[p], R[p*40+j], acc);
            float q = -LR_ * acc;
            qs2[i][j] = -2.f * q;
            qc[j] += q;
        }
    }

    // ec[j] = es[j]/16 + qc[j];  es[j] = -LR * sum_p R[p][j] z[p]
    float ec[6];
    #pragma unroll
    for (int j = 0; j < 6; ++j) {
        float acc = 0.f;
        #pragma unroll
        for (int p = 0; p < 8; ++p) acc = fmaf(R[p*40+j], z[p], acc);
        ec[j] = fmaf(-LR_ * 0.0625f, acc, qc[j]);
    }

    float u[6];
    #pragma unroll
    for (int j = 0; j < 6; ++j) u[j] = 0.5f;

    for (int step = 0; step < 200; ++step) {
        float r[4];
        #pragma unroll
        for (int i = 0; i < 4; ++i) {
            float t = b1k[i];
            #pragma unroll
            for (int j = 0; j < 6; ++j) t = fmaf(u[j], w1k[i][j], t);
            r[i] = __builtin_amdgcn_rcpf(__builtin_amdgcn_exp2f(t) + 1.f);
        }
        // per-lane partial: g = u/16 + ec + sum_i r_i * (-2 Qs[i][:])
        float g[6];
        #pragma unroll
        for (int j = 0; j < 6; ++j) g[j] = fmaf(u[j], 0.0625f, ec[j]);
        #pragma unroll
        for (int i = 0; i < 4; ++i)
            #pragma unroll
            for (int j = 0; j < 6; ++j)
                g[j] = fmaf(r[i], qs2[i][j], g[j]);
        // 16-lane allreduce: xor1, xor2, xor7, xor15 (all DPP, VALU pipe)
        #pragma unroll
        for (int j = 0; j < 6; ++j) {
            g[j] += dppx<0xB1>(g[j]);    // quad_perm [1,0,3,2]
            g[j] += dppx<0x4E>(g[j]);    // quad_perm [2,3,0,1]
            g[j] += dppx<0x141>(g[j]);   // row_half_mirror
            g[j] += dppx<0x140>(g[j]);   // row_mirror
            u[j] = __builtin_amdgcn_fmed3f(g[j], 0.f, 1.f);
        }
    }

    if (live && sub == 0) {
        float* o = out + s * 6;
        #pragma unroll
        for (int j = 0; j < 6; ++j) o[j] = u[j];
    }
}

extern "C" void kernel_launch(void* const* d_in, const int* in_sizes, int n_in,
                              void* d_out, int out_size, void* d_ws, size_t ws_size,
                              hipStream_t stream)
{
    const float* spec = (const float*)d_in[0];  // (B,40)
    const float* W1   = (const float*)d_in[1];  // (6,64)
    const float* b1   = (const float*)d_in[2];  // (64,)
    const float* W2   = (const float*)d_in[3];  // (64,40)
    const float* b2   = (const float*)d_in[4];  // (40,)
    const float* R    = (const float*)d_in[5];  // (8,40)
    int batch = in_sizes[0] / 40;

    int threads = batch * 16;
    int blocks  = (threads + 255) / 256;
    hipLaunchKernelGGL(solve_k, dim3(blocks), dim3(256), 0, stream,
                       spec, W1, b1, W2, b2, R, (float*)d_out, batch);
}

// Round 6
// 186.925 us; speedup vs baseline: 1.2402x; 1.2402x over previous
//
#include <hip/hip_runtime.h>

// BackwardRPM: 16384 independent solves, 200 steps of
//   u <- clip(u - LR * (R^T (R (tanh(u W1 + b1) W2 + b2 - spec)))[:6])
// Algebra: Qs[i][j] = -LR * sum_p R[p][j] M_i[p], M_i[p] = sum_k W2[i][k]R[p][k]
//   es[j]  = -LR * sum_p R[p][j] z[p],  z[p] = sum_k R[p][k](b2[k]-spec[k])
//   tanh(t)=1-2r, r=rcp(exp2(K(uW1+b1))+1), K=2log2(e)
//   u <- med3(u + es + sum_i Qs[i,:] + sum_i r_i*(-2Qs[i,:]), 0, 1)
//
// R6: the allocator NEVER kept constants resident (VGPR 124/64/64/100/52 over
// R1-R5; launch_bounds, waves_per_eu, asm pins all failed -> in-loop remat,
// ~2.6-2.8x instr inflation). Fix: the whole 200-step loop is ONE asm volatile
// block with hard registers. Constants load inside the asm (24x dwordx4 from a
// packed ws table) into v22..v125 -- remat/spill impossible. 8 lanes/sample,
// 2048 waves = 2/SIMD. 153 instr/step; DPP hazards spaced >=5 by round-robin.
//
// ws layout (floats): [i*12+j] = K*W1[j][i], [i*12+6+j] = -2*Qs[i][j] (= +2LR*acc)
//                     [768+i] = K*b1[i], [832+p] = sum_k R[p][k] b2[k]

static constexpr float LR_ = 0.01f;

__global__ void setup_k(const float* __restrict__ W1, const float* __restrict__ b1,
                        const float* __restrict__ W2, const float* __restrict__ b2,
                        const float* __restrict__ R,  float* __restrict__ ws)
{
    const float K = 2.8853900817779268f;  // 2*log2(e)
    int i = threadIdx.x;
    if (i < 64) {
        float M[8];
        #pragma unroll
        for (int p = 0; p < 8; ++p) {
            float acc = 0.f;
            for (int k = 0; k < 40; ++k) acc = fmaf(W2[i*40+k], R[p*40+k], acc);
            M[p] = acc;
        }
        #pragma unroll
        for (int j = 0; j < 6; ++j) {
            float acc = 0.f;
            #pragma unroll
            for (int p = 0; p < 8; ++p) acc = fmaf(M[p], R[p*40+j], acc);
            ws[i*12 + j]     = K * W1[j*64 + i];   // W1 is (6,64) row-major
            ws[i*12 + 6 + j] = 2.f * LR_ * acc;    // -2*Qs
        }
        ws[768 + i] = K * b1[i];
    }
    if (i >= 64 && i < 72) {
        int p = i - 64;
        float acc = 0.f;
        for (int k = 0; k < 40; ++k) acc = fmaf(R[p*40+k], b2[k], acc);
        ws[832 + p] = acc;
    }
}

__global__ __launch_bounds__(256, 2) void solve_k(
    const float* __restrict__ spec, const float* __restrict__ R,
    const float* __restrict__ ws,   float* __restrict__ out, int batch)
{
    const int tid = blockIdx.x * 256 + threadIdx.x;
    const int s   = tid >> 3;
    const int sub = tid & 7;
    const int ib  = sub * 8;
    const bool live = (s < batch);
    const int sl = live ? s : 0;

    // ---- per-sample / per-thread small constants in C ----
    // z[p] = (R b2)[p] - sum_k R[p][k] spec[k]
    float z[8];
    #pragma unroll
    for (int p = 0; p < 8; ++p) z[p] = ws[832 + p];
    const float* sp = spec + sl * 40;
    for (int k = 0; k < 40; ++k) {
        float v = sp[k];
        #pragma unroll
        for (int p = 0; p < 8; ++p) z[p] = fmaf(-R[p*40+k], v, z[p]);
    }
    // qc[j] = sum_{my units} Qs[i][j] = -0.5 * sum ws[(ib+i)*12+6+j]
    float qc[6];
    #pragma unroll
    for (int j = 0; j < 6; ++j) qc[j] = 0.f;
    #pragma unroll
    for (int i = 0; i < 8; ++i)
        #pragma unroll
        for (int j = 0; j < 6; ++j) qc[j] += ws[(ib+i)*12 + 6 + j];
    // ec[j] = es[j]/8 + qc[j];  es[j] = -LR * sum_p R[p][j] z[p]
    float ec[6];
    #pragma unroll
    for (int j = 0; j < 6; ++j) {
        float acc = 0.f;
        #pragma unroll
        for (int p = 0; p < 8; ++p) acc = fmaf(R[p*40+j], z[p], acc);
        ec[j] = fmaf(-LR_ * 0.125f, acc, -0.5f * qc[j]);
    }

    const float* pw = ws + ib * 12;   // my 96-float slice (8 units x 12)
    const float* pb = ws + 768 + ib;  // my 8 b1k floats

    float o0, o1, o2, o3, o4, o5;
    // Register map (hard regs, all clobbered):
    //  v0-v5  g[6]     v6-v13 t/r[8]    v14 0.125      v15-v20 u[6]
    //  v22-v117 slice: w1k[ii][j]=v(22+12ii+j), qs2[ii][j]=v(28+12ii+j)
    //  v118-v125 b1k[ii]
    asm volatile(
        // ---- load constants into fixed regs ----
        "global_load_dwordx4 v[22:25],   %[pw], off            \n"
        "global_load_dwordx4 v[26:29],   %[pw], off offset:16  \n"
        "global_load_dwordx4 v[30:33],   %[pw], off offset:32  \n"
        "global_load_dwordx4 v[34:37],   %[pw], off offset:48  \n"
        "global_load_dwordx4 v[38:41],   %[pw], off offset:64  \n"
        "global_load_dwordx4 v[42:45],   %[pw], off offset:80  \n"
        "global_load_dwordx4 v[46:49],   %[pw], off offset:96  \n"
        "global_load_dwordx4 v[50:53],   %[pw], off offset:112 \n"
        "global_load_dwordx4 v[54:57],   %[pw], off offset:128 \n"
        "global_load_dwordx4 v[58:61],   %[pw], off offset:144 \n"
        "global_load_dwordx4 v[62:65],   %[pw], off offset:160 \n"
        "global_load_dwordx4 v[66:69],   %[pw], off offset:176 \n"
        "global_load_dwordx4 v[70:73],   %[pw], off offset:192 \n"
        "global_load_dwordx4 v[74:77],   %[pw], off offset:208 \n"
        "global_load_dwordx4 v[78:81],   %[pw], off offset:224 \n"
        "global_load_dwordx4 v[82:85],   %[pw], off offset:240 \n"
        "global_load_dwordx4 v[86:89],   %[pw], off offset:256 \n"
        "global_load_dwordx4 v[90:93],   %[pw], off offset:272 \n"
        "global_load_dwordx4 v[94:97],   %[pw], off offset:288 \n"
        "global_load_dwordx4 v[98:101],  %[pw], off offset:304 \n"
        "global_load_dwordx4 v[102:105], %[pw], off offset:320 \n"
        "global_load_dwordx4 v[106:109], %[pw], off offset:336 \n"
        "global_load_dwordx4 v[110:113], %[pw], off offset:352 \n"
        "global_load_dwordx4 v[114:117], %[pw], off offset:368 \n"
        "global_load_dwordx4 v[118:121], %[pb], off            \n"
        "global_load_dwordx4 v[122:125], %[pb], off offset:16  \n"
        "v_mov_b32 v14, 0x3e000000                             \n" // 0.125
        "v_mov_b32 v15, 0.5 \n v_mov_b32 v16, 0.5 \n v_mov_b32 v17, 0.5 \n"
        "v_mov_b32 v18, 0.5 \n v_mov_b32 v19, 0.5 \n v_mov_b32 v20, 0.5 \n"
        "s_mov_b32 s90, 200                                    \n"
        "s_waitcnt vmcnt(0)                                    \n"
        "L_step_%=:                                            \n"
        // t_ii = b1k_ii + sum_j u_j * w1k[ii][j]   (j outer, ii inner)
        "v_fma_f32 v6,  v15, v22,  v118 \n v_fma_f32 v7,  v15, v34,  v119 \n"
        "v_fma_f32 v8,  v15, v46,  v120 \n v_fma_f32 v9,  v15, v58,  v121 \n"
        "v_fma_f32 v10, v15, v70,  v122 \n v_fma_f32 v11, v15, v82,  v123 \n"
        "v_fma_f32 v12, v15, v94,  v124 \n v_fma_f32 v13, v15, v106, v125 \n"
        "v_fma_f32 v6,  v16, v23,  v6  \n v_fma_f32 v7,  v16, v35,  v7  \n"
        "v_fma_f32 v8,  v16, v47,  v8  \n v_fma_f32 v9,  v16, v59,  v9  \n"
        "v_fma_f32 v10, v16, v71,  v10 \n v_fma_f32 v11, v16, v83,  v11 \n"
        "v_fma_f32 v12, v16, v95,  v12 \n v_fma_f32 v13, v16, v107, v13 \n"
        "v_fma_f32 v6,  v17, v24,  v6  \n v_fma_f32 v7,  v17, v36,  v7  \n"
        "v_fma_f32 v8,  v17, v48,  v8  \n v_fma_f32 v9,  v17, v60,  v9  \n"
        "v_fma_f32 v10, v17, v72,  v10 \n v_fma_f32 v11, v17, v84,  v11 \n"
        "v_fma_f32 v12, v17, v96,  v12 \n v_fma_f32 v13, v17, v108, v13 \n"
        "v_fma_f32 v6,  v18, v25,  v6  \n v_fma_f32 v7,  v18, v37,  v7  \n"
        "v_fma_f32 v8,  v18, v49,  v8  \n v_fma_f32 v9,  v18, v61,  v9  \n"
        "v_fma_f32 v10, v18, v73,  v10 \n v_fma_f32 v11, v18, v85,  v11 \n"
        "v_fma_f32 v12, v18, v97,  v12 \n v_fma_f32 v13, v18, v109, v13 \n"
        "v_fma_f32 v6,  v19, v26,  v6  \n v_fma_f32 v7,  v19, v38,  v7  \n"
        "v_fma_f32 v8,  v19, v50,  v8  \n v_fma_f32 v9,  v19, v62,  v9  \n"
        "v_fma_f32 v10, v19, v74,  v10 \n v_fma_f32 v11, v19, v86,  v11 \n"
        "v_fma_f32 v12, v19, v98,  v12 \n v_fma_f32 v13, v19, v110, v13 \n"
        "v_fma_f32 v6,  v20, v27,  v6  \n v_fma_f32 v7,  v20, v39,  v7  \n"
        "v_fma_f32 v8,  v20, v51,  v8  \n v_fma_f32 v9,  v20, v63,  v9  \n"
        "v_fma_f32 v10, v20, v75,  v10 \n v_fma_f32 v11, v20, v87,  v11 \n"
        "v_fma_f32 v12, v20, v99,  v12 \n v_fma_f32 v13, v20, v111, v13 \n"
        // r = rcp(exp2(t) + 1)
        "v_exp_f32 v6, v6  \n v_exp_f32 v7, v7  \n v_exp_f32 v8, v8  \n"
        "v_exp_f32 v9, v9  \n v_exp_f32 v10, v10 \n v_exp_f32 v11, v11 \n"
        "v_exp_f32 v12, v12 \n v_exp_f32 v13, v13 \n"
        "v_add_f32 v6, 1.0, v6  \n v_add_f32 v7, 1.0, v7  \n"
        "v_add_f32 v8, 1.0, v8  \n v_add_f32 v9, 1.0, v9  \n"
        "v_add_f32 v10, 1.0, v10 \n v_add_f32 v11, 1.0, v11 \n"
        "v_add_f32 v12, 1.0, v12 \n v_add_f32 v13, 1.0, v13 \n"
        "v_rcp_f32 v6, v6  \n v_rcp_f32 v7, v7  \n v_rcp_f32 v8, v8  \n"
        "v_rcp_f32 v9, v9  \n v_rcp_f32 v10, v10 \n v_rcp_f32 v11, v11 \n"
        "v_rcp_f32 v12, v12 \n v_rcp_f32 v13, v13 \n"
        // g_j = 0.125*u_j + ec_j
        "v_fma_f32 v0, v14, v15, %[e0] \n v_fma_f32 v1, v14, v16, %[e1] \n"
        "v_fma_f32 v2, v14, v17, %[e2] \n v_fma_f32 v3, v14, v18, %[e3] \n"
        "v_fma_f32 v4, v14, v19, %[e4] \n v_fma_f32 v5, v14, v20, %[e5] \n"
        // g_j += r_ii * qs2[ii][j]   (ii outer, j inner)
        "v_fma_f32 v0, v6, v28, v0 \n v_fma_f32 v1, v6, v29, v1 \n"
        "v_fma_f32 v2, v6, v30, v2 \n v_fma_f32 v3, v6, v31, v3 \n"
        "v_fma_f32 v4, v6, v32, v4 \n v_fma_f32 v5, v6, v33, v5 \n"
        "v_fma_f32 v0, v7, v40, v0 \n v_fma_f32 v1, v7, v41, v1 \n"
        "v_fma_f32 v2, v7, v42, v2 \n v_fma_f32 v3, v7, v43, v3 \n"
        "v_fma_f32 v4, v7, v44, v4 \n v_fma_f32 v5, v7, v45, v5 \n"
        "v_fma_f32 v0, v8, v52, v0 \n v_fma_f32 v1, v8, v53, v1 \n"
        "v_fma_f32 v2, v8, v54, v2 \n v_fma_f32 v3, v8, v55, v3 \n"
        "v_fma_f32 v4, v8, v56, v4 \n v_fma_f32 v5, v8, v57, v5 \n"
        "v_fma_f32 v0, v9, v64, v0 \n v_fma_f32 v1, v9, v65, v1 \n"
        "v_fma_f32 v2, v9, v66, v2 \n v_fma_f32 v3, v9, v67, v3 \n"
        "v_fma_f32 v4, v9, v68, v4 \n v_fma_f32 v5, v9, v69, v5 \n"
        "v_fma_f32 v0, v10, v76, v0 \n v_fma_f32 v1, v10, v77, v1 \n"
        "v_fma_f32 v2, v10, v78, v2 \n v_fma_f32 v3, v10, v79, v3 \n"
        "v_fma_f32 v4, v10, v80, v4 \n v_fma_f32 v5, v10, v81, v5 \n"
        "v_fma_f32 v0, v11, v88, v0 \n v_fma_f32 v1, v11, v89, v1 \n"
        "v_fma_f32 v2, v11, v90, v2 \n v_fma_f32 v3, v11, v91, v3 \n"
        "v_fma_f32 v4, v11, v92, v4 \n v_fma_f32 v5, v11, v93, v5 \n"
        "v_fma_f32 v0, v12, v100, v0 \n v_fma_f32 v1, v12, v101, v1 \n"
        "v_fma_f32 v2, v12, v102, v2 \n v_fma_f32 v3, v12, v103, v3 \n"
        "v_fma_f32 v4, v12, v104, v4 \n v_fma_f32 v5, v12, v105, v5 \n"
        "v_fma_f32 v0, v13, v112, v0 \n v_fma_f32 v1, v13, v113, v1 \n"
        "v_fma_f32 v2, v13, v114, v2 \n v_fma_f32 v3, v13, v115, v3 \n"
        "v_fma_f32 v4, v13, v116, v4 \n v_fma_f32 v5, v13, v117, v5 \n"
        // 8-lane allreduce: xor1, xor2, xor7 (round-robin spaces DPP hazards)
        "v_add_f32_dpp v0, v0, v0 quad_perm:[1,0,3,2] row_mask:0xf bank_mask:0xf \n"
        "v_add_f32_dpp v1, v1, v1 quad_perm:[1,0,3,2] row_mask:0xf bank_mask:0xf \n"
        "v_add_f32_dpp v2, v2, v2 quad_perm:[1,0,3,2] row_mask:0xf bank_mask:0xf \n"
        "v_add_f32_dpp v3, v3, v3 quad_perm:[1,0,3,2] row_mask:0xf bank_mask:0xf \n"
        "v_add_f32_dpp v4, v4, v4 quad_perm:[1,0,3,2] row_mask:0xf bank_mask:0xf \n"
        "v_add_f32_dpp v5, v5, v5 quad_perm:[1,0,3,2] row_mask:0xf bank_mask:0xf \n"
        "v_add_f32_dpp v0, v0, v0 quad_perm:[2,3,0,1] row_mask:0xf bank_mask:0xf \n"
        "v_add_f32_dpp v1, v1, v1 quad_perm:[2,3,0,1] row_mask:0xf bank_mask:0xf \n"
        "v_add_f32_dpp v2, v2, v2 quad_perm:[2,3,0,1] row_mask:0xf bank_mask:0xf \n"
        "v_add_f32_dpp v3, v3, v3 quad_perm:[2,3,0,1] row_mask:0xf bank_mask:0xf \n"
        "v_add_f32_dpp v4, v4, v4 quad_perm:[2,3,0,1] row_mask:0xf bank_mask:0xf \n"
        "v_add_f32_dpp v5, v5, v5 quad_perm:[2,3,0,1] row_mask:0xf bank_mask:0xf \n"
        "v_add_f32_dpp v0, v0, v0 row_half_mirror row_mask:0xf bank_mask:0xf \n"
        "v_add_f32_dpp v1, v1, v1 row_half_mirror row_mask:0xf bank_mask:0xf \n"
        "v_add_f32_dpp v2, v2, v2 row_half_mirror row_mask:0xf bank_mask:0xf \n"
        "v_add_f32_dpp v3, v3, v3 row_half_mirror row_mask:0xf bank_mask:0xf \n"
        "v_add_f32_dpp v4, v4, v4 row_half_mirror row_mask:0xf bank_mask:0xf \n"
        "v_add_f32_dpp v5, v5, v5 row_half_mirror row_mask:0xf bank_mask:0xf \n"
        // u_j = med3(g_j, 0, 1)
        "v_med3_f32 v15, v0, 0, 1.0 \n v_med3_f32 v16, v1, 0, 1.0 \n"
        "v_med3_f32 v17, v2, 0, 1.0 \n v_med3_f32 v18, v3, 0, 1.0 \n"
        "v_med3_f32 v19, v4, 0, 1.0 \n v_med3_f32 v20, v5, 0, 1.0 \n"
        "s_sub_u32 s90, s90, 1     \n"
        "s_cmp_lg_u32 s90, 0       \n"
        "s_cbranch_scc1 L_step_%=  \n"
        "v_mov_b32 %[o0], v15 \n v_mov_b32 %[o1], v16 \n v_mov_b32 %[o2], v17 \n"
        "v_mov_b32 %[o3], v18 \n v_mov_b32 %[o4], v19 \n v_mov_b32 %[o5], v20 \n"
        : [o0] "=v"(o0), [o1] "=v"(o1), [o2] "=v"(o2),
          [o3] "=v"(o3), [o4] "=v"(o4), [o5] "=v"(o5)
        : [pw] "v"(pw), [pb] "v"(pb),
          [e0] "v"(ec[0]), [e1] "v"(ec[1]), [e2] "v"(ec[2]),
          [e3] "v"(ec[3]), [e4] "v"(ec[4]), [e5] "v"(ec[5])
        : "v0","v1","v2","v3","v4","v5","v6","v7","v8","v9","v10","v11","v12",
          "v13","v14","v15","v16","v17","v18","v19","v20","v21","v22","v23",
          "v24","v25","v26","v27","v28","v29","v30","v31","v32","v33","v34",
          "v35","v36","v37","v38","v39","v40","v41","v42","v43","v44","v45",
          "v46","v47","v48","v49","v50","v51","v52","v53","v54","v55","v56",
          "v57","v58","v59","v60","v61","v62","v63","v64","v65","v66","v67",
          "v68","v69","v70","v71","v72","v73","v74","v75","v76","v77","v78",
          "v79","v80","v81","v82","v83","v84","v85","v86","v87","v88","v89",
          "v90","v91","v92","v93","v94","v95","v96","v97","v98","v99","v100",
          "v101","v102","v103","v104","v105","v106","v107","v108","v109",
          "v110","v111","v112","v113","v114","v115","v116","v117","v118",
          "v119","v120","v121","v122","v123","v124","v125",
          "s90","scc");

    if (live && sub == 0) {
        float* o = out + s * 6;
        o[0] = o0; o[1] = o1; o[2] = o2; o[3] = o3; o[4] = o4; o[5] = o5;
    }
}

extern "C" void kernel_launch(void* const* d_in, const int* in_sizes, int n_in,
                              void* d_out, int out_size, void* d_ws, size_t ws_size,
                              hipStream_t stream)
{
    const float* spec = (const float*)d_in[0];  // (B,40)
    const float* W1   = (const float*)d_in[1];  // (6,64)
    const float* b1   = (const float*)d_in[2];  // (64,)
    const float* W2   = (const float*)d_in[3];  // (64,40)
    const float* b2   = (const float*)d_in[4];  // (40,)
    const float* R    = (const float*)d_in[5];  // (8,40)
    float* ws = (float*)d_ws;
    int batch = in_sizes[0] / 40;

    hipLaunchKernelGGL(setup_k, dim3(1), dim3(128), 0, stream, W1, b1, W2, b2, R, ws);

    int threads = batch * 8;
    int blocks  = (threads + 255) / 256;
    hipLaunchKernelGGL(solve_k, dim3(blocks), dim3(256), 0, stream,
                       spec, R, ws, (float*)d_out, batch);
}